// Round 4
// baseline (14878.467 us; speedup 1.0000x reference)
//
#include <hip/hip_runtime.h>

typedef unsigned int u32;
typedef unsigned short u16;
typedef unsigned long long u64;

typedef __attribute__((ext_vector_type(8))) short bf16x8;
typedef __attribute__((ext_vector_type(4))) float f32x4;

__device__ __forceinline__ u16 f2bf(float f) {
    u32 u = __float_as_uint(f);
    u += 0x7fffu + ((u >> 16) & 1u);
    return (u16)(u >> 16);
}
__device__ __forceinline__ float bf2f(u16 h) {
    return __uint_as_float(((u32)h) << 16);
}

// ---------------------------------------------------------------------------
// prep: convert/transpose weights to bf16
// W1T[1200][200], W2T[600][400], U1T[1200][400], U2T[600][200]
// ---------------------------------------------------------------------------
__global__ __launch_bounds__(256) void prep_kernel(
    const float* __restrict__ W1, const float* __restrict__ W2,
    const float* __restrict__ U1, const float* __restrict__ U2,
    u16* __restrict__ W1T, u16* __restrict__ W2T,
    u16* __restrict__ U1T, u16* __restrict__ U2T)
{
    int i = blockIdx.x * 256 + threadIdx.x;
    if (i < 240000) { int j = i / 200, k = i - j * 200; W1T[i] = f2bf(W1[k * 1200 + j]); return; }
    i -= 240000;
    if (i < 240000) { int j = i / 400, k = i - j * 400; W2T[i] = f2bf(W2[k * 600 + j]); return; }
    i -= 240000;
    if (i < 480000) { int j = i / 400, k = i - j * 400; U1T[i] = f2bf(U1[k * 1200 + j]); return; }
    i -= 480000;
    if (i < 120000) { int j = i / 200, k = i - j * 200; U2T[i] = f2bf(U2[k * 600 + j]); }
}

// ---------------------------------------------------------------------------
// embed + batchnorm -> x bf16, layout [t*128 + b][200]
// ---------------------------------------------------------------------------
__global__ __launch_bounds__(256) void embed_bn_kernel(
    const int* __restrict__ tokens, const float* __restrict__ emb,
    const float* __restrict__ gamma, const float* __restrict__ beta,
    const float* __restrict__ mmean, const float* __restrict__ mvar,
    u16* __restrict__ x)
{
    int gid = blockIdx.x * 256 + threadIdx.x;  // 6,553,600 total
    int r = gid / 200, e = gid - r * 200;
    int t = r >> 7, b = r & 127;               // r = t*128 + b
    int tok = tokens[b * 256 + t];
    float v = (emb[(size_t)tok * 200 + e] - mmean[e]) *
              (1.0f / sqrtf(mvar[e] + 1e-3f)) * gamma[e] + beta[e];
    x[gid] = f2bf(v);
}

// ---------------------------------------------------------------------------
// GEMM: C[M][N] (bf16) = A[M][KEL] (bf16) @ B[KEL][N] + bias, B given as
// BT[N][KEL]. Tile 64x64 per 256-thread WG; MFMA 16x16x32 bf16.
// ---------------------------------------------------------------------------
template<int KEL, int KSTEPS, int KPAD>
__global__ __launch_bounds__(256) void gemm_bias_kernel(
    const u16* __restrict__ A, const u16* __restrict__ BT,
    const float* __restrict__ bias, u16* __restrict__ C, int N)
{
    __shared__ u16 A_lds[64 * KPAD];
    __shared__ u16 B_lds[64 * KPAD];
    const int m0 = blockIdx.x * 64, n0 = blockIdx.y * 64;
    const int tid = threadIdx.x;
    const int lane = tid & 63, wave = tid >> 6;
    const int l15 = lane & 15, lq = lane >> 4;

    for (int idx = tid; idx < 64 * (KPAD / 2); idx += 256) {
        int row = idx / (KPAD / 2), kp = idx % (KPAD / 2);
        int k = kp * 2;
        u32 va = (k < KEL) ? *(const u32*)(A + (size_t)(m0 + row) * KEL + k) : 0u;
        *(u32*)(A_lds + row * KPAD + k) = va;
        int gn = n0 + row;
        u32 vb = (k < KEL && gn < N) ? *(const u32*)(BT + (size_t)gn * KEL + k) : 0u;
        *(u32*)(B_lds + row * KPAD + k) = vb;
    }
    __syncthreads();

    f32x4 acc[4];
    for (int i = 0; i < 4; ++i) acc[i] = (f32x4){0.f, 0.f, 0.f, 0.f};
    for (int ks = 0; ks < KSTEPS; ++ks) {
        bf16x8 a = *(const bf16x8*)(A_lds + (wave * 16 + l15) * KPAD + ks * 32 + lq * 8);
        for (int nt = 0; nt < 4; ++nt) {
            bf16x8 b = *(const bf16x8*)(B_lds + (nt * 16 + l15) * KPAD + ks * 32 + lq * 8);
            acc[nt] = __builtin_amdgcn_mfma_f32_16x16x32_bf16(a, b, acc[nt], 0, 0, 0);
        }
    }
    for (int nt = 0; nt < 4; ++nt) {
        int col = n0 + nt * 16 + l15;
        if (col < N) {
            float bv = bias[col];
            for (int i = 0; i < 4; ++i) {
                int row = m0 + wave * 16 + lq * 4 + i;
                C[(size_t)row * N + col] = f2bf(acc[nt][i] + bv);
            }
        }
    }
}

// ---------------------------------------------------------------------------
// Register-resident GRU scan: one WG per batch-group of 16, the ENTIRE
// recurrent matrix U held in VGPRs (wave w owns N-tiles w*NT..w*NT+NT-1,
// all K). h round-trips through LDS only; 2 __syncthreads per step; no
// cross-WG communication of any kind.
//   per step: [prefetch xw] -> barrier -> MFMA (h_lds x Breg) ->
//             rec->LDS -> barrier -> gates -> h_lds + global stores
// ---------------------------------------------------------------------------
template<int UH, int NW, int NT, int KSTEPS, int KPAD, int RECP, int MAXE,
         bool WB16>
__global__ __launch_bounds__(NW * 64, 4) void gru_reg_kernel(
    const u16* __restrict__ xw,      // [256*128][3*UH] bf16 (row = t*128+b)
    const u16* __restrict__ UT,      // [3*UH][UH] bf16 (transposed U)
    const float* __restrict__ br,    // [3*UH] recurrent bias
    const int* __restrict__ tokens,  // [128][256]
    float* __restrict__ out_f32,     // [128][256][UH]
    u16* __restrict__ out_b16,       // [256*128][UH] or unused
    float* __restrict__ h_final)     // [128][UH]
{
    constexpr int NTH = NW * 64;
    __shared__ u16 h_lds[16 * KPAD];
    __shared__ float rec_lds[16 * RECP];

    const int tid = threadIdx.x;
    const int b0 = blockIdx.x * 16;
    const int lane = tid & 63, wave = tid >> 6;
    const int l15 = lane & 15, lq = lane >> 4;

    // zero h_lds (incl. K padding — read as zeros by MFMA forever)
    for (int i = tid; i < 16 * KPAD / 2; i += NTH) ((u32*)h_lds)[i] = 0u;

    // load this wave's U slice into registers (once)
    bf16x8 Breg[NT][KSTEPS];
    for (int nt = 0; nt < NT; ++nt) {
        int n = (wave * NT + nt) * 16 + l15;
        for (int ks = 0; ks < KSTEPS; ++ks) {
            int k = ks * 32 + lq * 8;
            bf16x8 v = {0, 0, 0, 0, 0, 0, 0, 0};
            if (n < 3 * UH && k < UH)
                v = *(const bf16x8*)(UT + (size_t)n * UH + k);
            Breg[nt][ks] = v;
        }
    }

    // per-thread gate-element mapping (step-invariant)
    int ne = 0;
    int eb[MAXE], ecol[MAXE], pxw[MAXE], pout[MAXE], pb16[MAXE], ptok[MAXE];
    float brz[MAXE], brr[MAXE], brh[MAXE], hold[MAXE];
    for (int i = 0; i < MAXE; ++i) {
        int u = tid + i * NTH;
        if (u < 16 * UH) {
            int b = u / UH, col = u - b * UH, gb = b0 + b;
            eb[ne] = b; ecol[ne] = col;
            pxw[ne] = gb * 3 * UH + col;
            pout[ne] = gb * 256 * UH + col;
            pb16[ne] = gb * UH + col;
            ptok[ne] = gb * 256;
            brz[ne] = br[col]; brr[ne] = br[UH + col]; brh[ne] = br[2 * UH + col];
            hold[ne] = 0.f;
            ++ne;
        }
    }
    __syncthreads();

    for (int t = 0; t < 256; ++t) {
        // 1. prefetch this step's gate inputs (no LDS deps — overlaps barrier)
        float xz[MAXE], xr[MAXE], xh[MAXE];
        int tk[MAXE];
        const int tof = t * (128 * 3 * UH);
        for (int e = 0; e < ne; ++e) {
            const u16* p = xw + (size_t)tof + pxw[e];
            xz[e] = bf2f(p[0]);
            xr[e] = bf2f(p[UH]);
            xh[e] = bf2f(p[2 * UH]);
            tk[e] = tokens[ptok[e] + t];
        }
        __syncthreads();   // h_lds(t-1) writes done; rec_lds free

        // 2. rec = h @ U  (A from LDS, B from registers)
        bf16x8 A[KSTEPS];
        for (int ks = 0; ks < KSTEPS; ++ks)
            A[ks] = *(const bf16x8*)(h_lds + l15 * KPAD + ks * 32 + lq * 8);
        f32x4 acc[NT];
        for (int nt = 0; nt < NT; ++nt) acc[nt] = (f32x4){0.f, 0.f, 0.f, 0.f};
        for (int ks = 0; ks < KSTEPS; ++ks)
            for (int nt = 0; nt < NT; ++nt)
                acc[nt] = __builtin_amdgcn_mfma_f32_16x16x32_bf16(
                    A[ks], Breg[nt][ks], acc[nt], 0, 0, 0);
        for (int nt = 0; nt < NT; ++nt) {
            int cb = (wave * NT + nt) * 16 + l15;
            for (int i = 0; i < 4; ++i)
                rec_lds[(lq * 4 + i) * RECP + cb] = acc[nt][i];
        }
        __syncthreads();

        // 3. gates + state update + stores
        for (int e = 0; e < ne; ++e) {
            int b = eb[e], col = ecol[e];
            float rz = rec_lds[b * RECP + col] + brz[e];
            float rr = rec_lds[b * RECP + UH + col] + brr[e];
            float rh = rec_lds[b * RECP + 2 * UH + col] + brh[e];
            float z = 1.f / (1.f + __expf(-(xz[e] + rz)));
            float r = 1.f / (1.f + __expf(-(xr[e] + rr)));
            float pre = xh[e] + r * rh;
            float th = 2.f / (1.f + __expf(-2.f * pre)) - 1.f;
            float hn = z * hold[e] + (1.f - z) * th;
            if (tk[e] == 0) hn = hold[e];              // masked: carry state
            hold[e] = hn;
            u16 hv = f2bf(hn);
            h_lds[b * KPAD + col] = hv;                // next step's A
            out_f32[(size_t)pout[e] + (size_t)t * UH] = hn;
            if (WB16) out_b16[(size_t)pb16[e] + (size_t)t * (128 * UH)] = hv;
            if (t == 255) h_final[pb16[e]] = hn;
        }
    }
}

// ---------------------------------------------------------------------------
// launch
// ---------------------------------------------------------------------------
extern "C" void kernel_launch(void* const* d_in, const int* in_sizes, int n_in,
                              void* d_out, int out_size, void* d_ws, size_t ws_size,
                              hipStream_t stream)
{
    const int*   tokens = (const int*)d_in[0];
    const float* emb    = (const float*)d_in[1];
    const float* gamma  = (const float*)d_in[2];
    const float* beta   = (const float*)d_in[3];
    const float* mmean  = (const float*)d_in[4];
    const float* mvar   = (const float*)d_in[5];
    const float* W1     = (const float*)d_in[6];
    const float* U1     = (const float*)d_in[7];
    const float* b1     = (const float*)d_in[8];
    const float* W2     = (const float*)d_in[9];
    const float* U2     = (const float*)d_in[10];
    const float* b2     = (const float*)d_in[11];

    float* out = (float*)d_out;
    char* ws = (char*)d_ws;

    u16* x     = (u16*)(ws + 0);            // 32768*200*2  = 13,107,200
    u16* xw1   = (u16*)(ws + 13107200);     // 32768*1200*2 = 78,643,200
    u16* o1b   = (u16*)(ws + 91750400);     // 32768*400*2  = 26,214,400
    u16* xw2   = (u16*)(ws + 117964800);    // 32768*600*2  = 39,321,600
    u16* W1T   = (u16*)(ws + 157286400);    // 480,000
    u16* W2T   = (u16*)(ws + 157766400);    // 480,000
    u16* U1T   = (u16*)(ws + 158246400);    // 960,000
    u16* U2T   = (u16*)(ws + 159206400);    // 240,000

    float* out2 = out;              // [128,256,200]
    float* out1 = out + 6553600;    // [128,256,400]
    float* h2   = out + 19660800;   // [128,200]
    float* h1   = out + 19686400;   // [128,400]

    prep_kernel<<<4219, 256, 0, stream>>>(W1, W2, U1, U2, W1T, W2T, U1T, U2T);
    embed_bn_kernel<<<25600, 256, 0, stream>>>(tokens, emb, gamma, beta, mmean,
                                               mvar, x);
    // xw1 = x @ W1 + bi1   ([32768,200]@[200,1200])
    gemm_bias_kernel<200, 7, 232><<<dim3(512, 19), 256, 0, stream>>>(
        x, W1T, b1, xw1, 1200);
    // GRU1: UH=400, 16 waves x 5 N-tiles (80 tiles, 75 real), K=400->13 steps,
    // KPAD=440 / RECP=1284 (bank-conflict padding), 8 WGs (one per 16-batch)
    gru_reg_kernel<400, 16, 5, 13, 440, 1284, 7, true><<<8, 1024, 0, stream>>>(
        xw1, U1T, b1 + 1200, tokens, out1, o1b, h1);
    // xw2 = out1 @ W2 + bi2   ([32768,400]@[400,600])
    gemm_bias_kernel<400, 13, 424><<<dim3(512, 10), 256, 0, stream>>>(
        o1b, W2T, b2, xw2, 600);
    // GRU2: UH=200, 8 waves x 5 N-tiles (40 tiles), K=200->7 steps,
    // KPAD=232 / RECP=644
    gru_reg_kernel<200, 8, 5, 7, 232, 644, 7, false><<<8, 512, 0, stream>>>(
        xw2, U2T, b2 + 600, tokens, out2, (u16*)nullptr, h2);
}